// Round 1
// baseline (532.445 us; speedup 1.0000x reference)
//
#include <hip/hip_runtime.h>
#include <hip/hip_bf16.h>

#define BB 4
#define CMv 256
#define CTv 64
#define CAv 128
#define NTOK 6400

typedef unsigned short u16;
typedef __attribute__((ext_vector_type(8))) short sh8;   // 8 bf16 (4 VGPRs)
typedef __attribute__((ext_vector_type(4))) short sh4;   // 4 bf16
typedef __attribute__((ext_vector_type(4))) float f32x4;

__device__ __forceinline__ u16 f2bf(float f) {
  unsigned u = __builtin_bit_cast(unsigned, f);
  unsigned r = (u + 0x7FFFu + ((u >> 16) & 1u)) >> 16;  // RNE
  return (u16)r;
}

// ---------------- Kernel A1: Q projection ----------------
// q[b,ch,i] = sum_cin wq[ch,cin]*met[b,cin,i] + bq[ch]; stored token-major bf16 [B][N][CA]
__global__ __launch_bounds__(256) void qproj(const float* __restrict__ met,
                                             const float* __restrict__ wq,
                                             const float* __restrict__ bq,
                                             u16* __restrict__ Qtm) {
  int bx = blockIdx.x;                 // B * 25 * 4 = 400
  int chg = bx & 3;
  int t256 = (bx >> 2) % 25;
  int b = bx / 100;
  int i = t256 * 256 + threadIdx.x;
  const float* mp = met + (size_t)b * CMv * NTOK + i;
  const float* wrow = wq + chg * 32 * CMv;
  float acc[32];
#pragma unroll
  for (int j = 0; j < 32; j++) acc[j] = bq[chg * 32 + j];
  for (int cin = 0; cin < CMv; cin += 4) {
    float v0 = mp[(size_t)(cin + 0) * NTOK];
    float v1 = mp[(size_t)(cin + 1) * NTOK];
    float v2 = mp[(size_t)(cin + 2) * NTOK];
    float v3 = mp[(size_t)(cin + 3) * NTOK];
#pragma unroll
    for (int j = 0; j < 32; j++) {
      acc[j] = fmaf(wrow[j * CMv + cin + 0], v0, acc[j]);
      acc[j] = fmaf(wrow[j * CMv + cin + 1], v1, acc[j]);
      acc[j] = fmaf(wrow[j * CMv + cin + 2], v2, acc[j]);
      acc[j] = fmaf(wrow[j * CMv + cin + 3], v3, acc[j]);
    }
  }
  u16* qp = Qtm + ((size_t)b * NTOK + i) * CAv + chg * 32;
#pragma unroll
  for (int j = 0; j < 32; j++) qp[j] = f2bf(acc[j]);
}

// ---------------- Kernel A2: K,V projections ----------------
// K token-major bf16 [B][N][CA]; V channel-major bf16 [B][CA][N]
__global__ __launch_bounds__(256) void kvproj(const float* __restrict__ ter,
                                              const float* __restrict__ wk,
                                              const float* __restrict__ bk,
                                              const float* __restrict__ wv,
                                              const float* __restrict__ bv,
                                              u16* __restrict__ Ktm,
                                              u16* __restrict__ Vcm) {
  int bx = blockIdx.x;                 // 400
  int chg = bx & 3;
  int t256 = (bx >> 2) % 25;
  int b = bx / 100;
  int i = t256 * 256 + threadIdx.x;
  const float* tp = ter + (size_t)b * CTv * NTOK + i;
  const float* wkr = wk + chg * 32 * CTv;
  const float* wvr = wv + chg * 32 * CTv;
  float accK[32], accV[32];
#pragma unroll
  for (int j = 0; j < 32; j++) { accK[j] = bk[chg * 32 + j]; accV[j] = bv[chg * 32 + j]; }
  for (int cin = 0; cin < CTv; cin += 2) {
    float v0 = tp[(size_t)(cin + 0) * NTOK];
    float v1 = tp[(size_t)(cin + 1) * NTOK];
#pragma unroll
    for (int j = 0; j < 32; j++) {
      accK[j] = fmaf(wkr[j * CTv + cin + 0], v0, accK[j]);
      accK[j] = fmaf(wkr[j * CTv + cin + 1], v1, accK[j]);
      accV[j] = fmaf(wvr[j * CTv + cin + 0], v0, accV[j]);
      accV[j] = fmaf(wvr[j * CTv + cin + 1], v1, accV[j]);
    }
  }
  u16* kp = Ktm + ((size_t)b * NTOK + i) * CAv + chg * 32;
#pragma unroll
  for (int j = 0; j < 32; j++) kp[j] = f2bf(accK[j]);
#pragma unroll
  for (int j = 0; j < 32; j++)
    Vcm[((size_t)b * CAv + chg * 32 + j) * NTOK + i] = f2bf(accV[j]);
}

// ---------------- Kernel B: flash attention ----------------
// block = 256 thr (4 waves), each wave owns 16 q-rows; KV tiles of 32, staged in LDS.
// S^T = mfma(K_frag, Q_frag): D[kv=(l>>4)*4+r][q=l&15]  (verified C/D layout)
// PV:  O  = mfma(P_frag, V_frag): D[q=(l>>4)*4+r][c=l&15]
__global__ __launch_bounds__(256) void attn(const u16* __restrict__ Qtm,
                                            const u16* __restrict__ Ktm,
                                            const u16* __restrict__ Vcm,
                                            float* __restrict__ Otm) {
  __shared__ u16 Klds[32][136];   // pad 136: breaks 32-way bank conflict at D=128
  __shared__ u16 Vlds[128][40];   // channel-major V tile [c][kv], pad 40
  __shared__ u16 Plds[4][16][40]; // per-wave P re-layout buffer

  const int tid = threadIdx.x;
  const int wv = tid >> 6;
  const int lane = tid & 63;
  const int g = lane >> 4;
  const int i16 = lane & 15;
  const int b = blockIdx.x / (NTOK / 64);
  const int qt = blockIdx.x % (NTOK / 64);
  const int qbase = qt * 64;

  // Q B-fragments held in registers for the whole KV loop (K=128 -> 4 frags)
  const u16* qp = Qtm + ((size_t)b * NTOK + qbase + wv * 16 + i16) * CAv + g * 8;
  sh8 qf[4];
#pragma unroll
  for (int kk = 0; kk < 4; kk++) qf[kk] = *(const sh8*)(qp + kk * 32);

  f32x4 o[8];
#pragma unroll
  for (int ct = 0; ct < 8; ct++) o[ct] = (f32x4){0.f, 0.f, 0.f, 0.f};
  float m = -1e30f, lsum = 0.f;

  const int krow = tid >> 4;          // 0..15
  const int kcol = (tid & 15) * 8;    // 0..120
  const int vrow = tid >> 2;          // 0..63
  const int vcol = (tid & 3) * 8;     // 0..24
  const u16* kbase = Ktm + (size_t)b * NTOK * CAv;
  const u16* vbase = Vcm + (size_t)b * CAv * NTOK;

  // T14 async-stage: prefetch tile 0 into registers
  sh8 kreg0 = *(const sh8*)(kbase + (size_t)(krow) * CAv + kcol);
  sh8 kreg1 = *(const sh8*)(kbase + (size_t)(16 + krow) * CAv + kcol);
  sh8 vreg0 = *(const sh8*)(vbase + (size_t)vrow * NTOK + vcol);
  sh8 vreg1 = *(const sh8*)(vbase + (size_t)(64 + vrow) * NTOK + vcol);

  const float scale = 0.088388347648318447f;  // 128^-0.5

  for (int kt = 0; kt < NTOK / 32; kt++) {
    __syncthreads();                       // previous compute done
    *(sh8*)&Klds[krow][kcol] = kreg0;
    *(sh8*)&Klds[16 + krow][kcol] = kreg1;
    *(sh8*)&Vlds[vrow][vcol] = vreg0;
    *(sh8*)&Vlds[64 + vrow][vcol] = vreg1;
    __syncthreads();                       // tile visible
    if (kt + 1 < NTOK / 32) {              // issue next tile's loads early
      const int kvb = (kt + 1) * 32;
      kreg0 = *(const sh8*)(kbase + (size_t)(kvb + krow) * CAv + kcol);
      kreg1 = *(const sh8*)(kbase + (size_t)(kvb + 16 + krow) * CAv + kcol);
      vreg0 = *(const sh8*)(vbase + (size_t)vrow * NTOK + kvb + vcol);
      vreg1 = *(const sh8*)(vbase + (size_t)(64 + vrow) * NTOK + kvb + vcol);
    }
    // S^T = K·Q^T over c=128
    f32x4 st0 = {0.f, 0.f, 0.f, 0.f}, st1 = {0.f, 0.f, 0.f, 0.f};
#pragma unroll
    for (int kk = 0; kk < 4; kk++) {
      sh8 kf0 = *(const sh8*)&Klds[i16][kk * 32 + g * 8];
      sh8 kf1 = *(const sh8*)&Klds[16 + i16][kk * 32 + g * 8];
      st0 = __builtin_amdgcn_mfma_f32_16x16x32_bf16(kf0, qf[kk], st0, 0, 0, 0);
      st1 = __builtin_amdgcn_mfma_f32_16x16x32_bf16(kf1, qf[kk], st1, 0, 0, 0);
    }
    // online softmax: this lane holds S[q=i16][kv = kvb + t*16 + g*4 + r]
    float p0[4], p1[4];
    float pmax = -1e30f;
#pragma unroll
    for (int r = 0; r < 4; r++) {
      p0[r] = st0[r] * scale;
      p1[r] = st1[r] * scale;
      pmax = fmaxf(pmax, fmaxf(p0[r], p1[r]));
    }
    pmax = fmaxf(pmax, __shfl_xor(pmax, 16));
    pmax = fmaxf(pmax, __shfl_xor(pmax, 32));
    float mnew = fmaxf(m, pmax);
    float alpha = __expf(m - mnew);
    float psum = 0.f;
#pragma unroll
    for (int r = 0; r < 4; r++) {
      p0[r] = __expf(p0[r] - mnew);
      p1[r] = __expf(p1[r] - mnew);
      psum += p0[r] + p1[r];
    }
    psum += __shfl_xor(psum, 16);
    psum += __shfl_xor(psum, 32);
    lsum = lsum * alpha + psum;
    m = mnew;
    // P: D-layout -> A-layout via per-wave LDS tile (intra-wave, no barrier)
    sh4 pk0, pk1;
#pragma unroll
    for (int r = 0; r < 4; r++) {
      pk0[r] = (short)f2bf(p0[r]);
      pk1[r] = (short)f2bf(p1[r]);
    }
    *(sh4*)&Plds[wv][i16][g * 4] = pk0;
    *(sh4*)&Plds[wv][i16][16 + g * 4] = pk1;
    // rescale O: this lane's O-rows are q = g*4+r; stats live at lane q (i16=q)
    float ar0 = __shfl(alpha, g * 4 + 0);
    float ar1 = __shfl(alpha, g * 4 + 1);
    float ar2 = __shfl(alpha, g * 4 + 2);
    float ar3 = __shfl(alpha, g * 4 + 3);
#pragma unroll
    for (int ct = 0; ct < 8; ct++) {
      o[ct][0] *= ar0; o[ct][1] *= ar1; o[ct][2] *= ar2; o[ct][3] *= ar3;
    }
    sh8 pf = *(const sh8*)&Plds[wv][i16][g * 8];
#pragma unroll
    for (int ct = 0; ct < 8; ct++) {
      sh8 vf = *(const sh8*)&Vlds[ct * 16 + i16][g * 8];
      o[ct] = __builtin_amdgcn_mfma_f32_16x16x32_bf16(pf, vf, o[ct], 0, 0, 0);
    }
  }
  // epilogue: divide by lsum (per O-row) and store token-major f32 O
  float linv[4];
#pragma unroll
  for (int r = 0; r < 4; r++) linv[r] = 1.f / __shfl(lsum, g * 4 + r);
  float* op = Otm + ((size_t)b * NTOK + qbase + wv * 16) * CAv;
#pragma unroll
  for (int ct = 0; ct < 8; ct++) {
#pragma unroll
    for (int r = 0; r < 4; r++) {
      op[(size_t)(g * 4 + r) * CAv + ct * 16 + i16] = o[ct][r] * linv[r];
    }
  }
}

// ---------------- Kernel C: output projection + residual ----------------
__global__ __launch_bounds__(256) void outproj(const float* __restrict__ met,
                                               const float* __restrict__ wo,
                                               const float* __restrict__ bo,
                                               const float* __restrict__ Otm,
                                               float* __restrict__ out) {
  __shared__ float Olds[32][129];  // +1 pad
  const int tid = threadIdx.x;
  const int b = blockIdx.x / 200;
  const int tb = blockIdx.x % 200;
#pragma unroll
  for (int p = 0; p < 4; p++) {
    int idx = p * 256 + tid;
    int tok = idx >> 5;
    int chunk = idx & 31;
    const float4 v = *(const float4*)(Otm + ((size_t)b * NTOK + tb * 32 + tok) * CAv + chunk * 4);
    Olds[tok][chunk * 4 + 0] = v.x;
    Olds[tok][chunk * 4 + 1] = v.y;
    Olds[tok][chunk * 4 + 2] = v.z;
    Olds[tok][chunk * 4 + 3] = v.w;
  }
  __syncthreads();
  const int tok = tid & 31;
  const int chg = tid >> 5;
  float acc[32];
#pragma unroll
  for (int j = 0; j < 32; j++) acc[j] = 0.f;
  const float* wrow = wo + chg * 32 * CAv;
  for (int c = 0; c < CAv; c++) {
    float ov = Olds[tok][c];
#pragma unroll
    for (int j = 0; j < 32; j++) acc[j] = fmaf(wrow[j * CAv + c], ov, acc[j]);
  }
  const int gi = tb * 32 + tok;
#pragma unroll
  for (int j = 0; j < 32; j++) {
    int ch = chg * 32 + j;
    size_t idx = ((size_t)b * CMv + ch) * NTOK + gi;
    out[idx] = met[idx] + acc[j] + bo[ch];
  }
}

extern "C" void kernel_launch(void* const* d_in, const int* in_sizes, int n_in,
                              void* d_out, int out_size, void* d_ws, size_t ws_size,
                              hipStream_t stream) {
  const float* met = (const float*)d_in[0];
  const float* ter = (const float*)d_in[1];
  const float* wq = (const float*)d_in[2];
  const float* bq = (const float*)d_in[3];
  const float* wk = (const float*)d_in[4];
  const float* bk = (const float*)d_in[5];
  const float* wv = (const float*)d_in[6];
  const float* bv = (const float*)d_in[7];
  const float* wo = (const float*)d_in[8];
  const float* bo = (const float*)d_in[9];
  float* out = (float*)d_out;

  u16* Qtm = (u16*)d_ws;                               // B*N*CA bf16
  u16* Ktm = Qtm + (size_t)BB * NTOK * CAv;            // B*N*CA bf16
  u16* Vcm = Ktm + (size_t)BB * NTOK * CAv;            // B*CA*N bf16
  float* Otm = (float*)(Vcm + (size_t)BB * NTOK * CAv);// B*N*CA f32 (~32.8 MB total)

  qproj<<<dim3(400), dim3(256), 0, stream>>>(met, wq, bq, Qtm);
  kvproj<<<dim3(400), dim3(256), 0, stream>>>(ter, wk, bk, wv, bv, Ktm, Vcm);
  attn<<<dim3(400), dim3(256), 0, stream>>>(Qtm, Ktm, Vcm, Otm);
  outproj<<<dim3(800), dim3(256), 0, stream>>>(met, wo, bo, Otm, out);
}

// Round 2
// 315.948 us; speedup vs baseline: 1.6852x; 1.6852x over previous
//
#include <hip/hip_runtime.h>
#include <hip/hip_bf16.h>

#define BB 4
#define CMv 256
#define CTv 64
#define CAv 128
#define NTOK 6400
#define SCL 0.088388347648318447f  /* 128^-0.5, folded into Q at qproj */

typedef unsigned short u16;
typedef __attribute__((ext_vector_type(8))) short sh8;     // 8 bf16
typedef __attribute__((ext_vector_type(4))) float f32x4;
typedef __attribute__((ext_vector_type(16))) float f32x16;
typedef __attribute__((ext_vector_type(4))) unsigned uint4v;

__device__ __forceinline__ u16 f2bf(float f) {
  return __builtin_bit_cast(u16, __float2bfloat16(f));
}
__device__ __forceinline__ unsigned pk2(float a, float b) {
  return ((unsigned)f2bf(b) << 16) | (unsigned)f2bf(a);
}
__device__ __forceinline__ f32x16 zero16() {
  f32x16 z;
#pragma unroll
  for (int i = 0; i < 16; i++) z[i] = 0.f;
  return z;
}
typedef const __attribute__((address_space(1))) unsigned int* gas_p;
typedef __attribute__((address_space(3))) unsigned int* las_p;
__device__ __forceinline__ void gl_lds16(const u16* g, u16* l) {
  // 16B direct global->LDS DMA; LDS dest = uniform base + lane*16 (HW)
  __builtin_amdgcn_global_load_lds((gas_p)g, (las_p)l, 16, 0, 0);
}

// ---------------- weight transpose prep ----------------
__global__ __launch_bounds__(256) void prepw(const float* __restrict__ wq,
                                             const float* __restrict__ wk,
                                             const float* __restrict__ wv,
                                             const float* __restrict__ wo,
                                             float* __restrict__ wqT,
                                             float* __restrict__ wkT,
                                             float* __restrict__ wvT,
                                             float* __restrict__ woT) {
  int i0 = blockIdx.x * 256 + threadIdx.x;
  for (int idx = i0; idx < 256 * 128; idx += 32 * 256) {  // wqT[cin][128]
    int ch = idx & 127, cin = idx >> 7;
    wqT[idx] = wq[ch * CMv + cin];
  }
  for (int idx = i0; idx < 64 * 128; idx += 32 * 256) {   // wkT[cin][128]
    int ch = idx & 127, cin = idx >> 7;
    wkT[idx] = wk[ch * CTv + cin];
    wvT[idx] = wv[ch * CTv + cin];
  }
  for (int idx = i0; idx < 128 * 256; idx += 32 * 256) {  // woT[c][256]
    int ch = idx & 255, c = idx >> 8;
    woT[idx] = wo[ch * CAv + c];
  }
}

// ---------------- Q projection (scale folded) ----------------
__global__ __launch_bounds__(256) void qproj(const float* __restrict__ met,
                                             const float* __restrict__ wqT,
                                             const float* __restrict__ bq,
                                             u16* __restrict__ Qtm) {
  const int b = blockIdx.x / 100;
  const int tokb = (blockIdx.x % 100) * 64;
  const int tok = threadIdx.x & 63;
  const int chg = __builtin_amdgcn_readfirstlane(threadIdx.x >> 6);  // 0..3
  const float* wt = wqT + chg * 32;
  const float* mp = met + (size_t)b * CMv * NTOK + tokb + tok;
  float acc[32];
#pragma unroll
  for (int j = 0; j < 32; j++) acc[j] = bq[chg * 32 + j];
#pragma unroll 4
  for (int cin = 0; cin < CMv; cin++) {
    float x = mp[(size_t)cin * NTOK];
#pragma unroll
    for (int j = 0; j < 32; j++) acc[j] = fmaf(wt[cin * CAv + j], x, acc[j]);
  }
  u16* qp = Qtm + ((size_t)b * NTOK + tokb + tok) * CAv + chg * 32;
#pragma unroll
  for (int v = 0; v < 4; v++) {
    sh8 pkv;
#pragma unroll
    for (int e = 0; e < 8; e++) pkv[e] = (short)f2bf(acc[v * 8 + e] * SCL);
    *(sh8*)(qp + v * 8) = pkv;
  }
}

// ---------------- K,V projections ----------------
__global__ __launch_bounds__(512) void kvproj(const float* __restrict__ ter,
                                              const float* __restrict__ wkT,
                                              const float* __restrict__ bk,
                                              const float* __restrict__ wvT,
                                              const float* __restrict__ bv,
                                              u16* __restrict__ Ktm,
                                              u16* __restrict__ Vcm) {
  const int b = blockIdx.x / 100;
  const int tokb = (blockIdx.x % 100) * 64;
  const int tok = threadIdx.x & 63;
  const int grp = __builtin_amdgcn_readfirstlane(threadIdx.x >> 6);  // 0..7
  const bool isV = grp >= 4;
  const int chg = isV ? (grp - 4) : grp;                              // 0..3
  const float* wt = (isV ? wvT : wkT) + chg * 32;
  const float* bias = isV ? bv : bk;
  const float* tp = ter + (size_t)b * CTv * NTOK + tokb + tok;
  float acc[32];
#pragma unroll
  for (int j = 0; j < 32; j++) acc[j] = bias[chg * 32 + j];
#pragma unroll 4
  for (int cin = 0; cin < CTv; cin++) {
    float x = tp[(size_t)cin * NTOK];
#pragma unroll
    for (int j = 0; j < 32; j++) acc[j] = fmaf(wt[cin * CAv + j], x, acc[j]);
  }
  if (!isV) {
    u16* kp = Ktm + ((size_t)b * NTOK + tokb + tok) * CAv + chg * 32;
#pragma unroll
    for (int v = 0; v < 4; v++) {
      sh8 pkv;
#pragma unroll
      for (int e = 0; e < 8; e++) pkv[e] = (short)f2bf(acc[v * 8 + e]);
      *(sh8*)(kp + v * 8) = pkv;
    }
  } else {
    u16* vp = Vcm + ((size_t)b * CAv + chg * 32) * NTOK + tokb + tok;
#pragma unroll
    for (int j = 0; j < 32; j++) vp[(size_t)j * NTOK] = f2bf(acc[j]);
  }
}

// ---------------- flash attention ----------------
// 4 waves: (wq = wv&1) q-tile of 32 rows, (half = wv>>1) KV half. KVBLK=64.
// S^T = mfma32(K_frag, Q_frag): D[kv-row pat][q = lane&31] -> stats lane-local.
// PV: O^T = mfma32(V_frag, P_frag): D[c pat][q = lane&31].
// K-frags from global (L2-resident), V double-buffer in LDS via global_load_lds DMA
// with XOR-swizzled source addresses (read side applies same XOR).
__global__ __launch_bounds__(256, 2) void attn(const u16* __restrict__ Qtm,
                                               const u16* __restrict__ Ktm,
                                               const u16* __restrict__ Vcm,
                                               float* __restrict__ Otm) {
  __shared__ __align__(16) unsigned char smem[66560];  // V[2 buf][2 half][16KB] + stats

  const int tid = threadIdx.x;
  const int wv = tid >> 6;
  const int lane = tid & 63;
  const int l31 = lane & 31;
  const int h = lane >> 5;
  const bool hb = (h != 0);
  const int half = wv >> 1;
  const int wq = wv & 1;

  const int bs = (blockIdx.x & 7) * 50 + (blockIdx.x >> 3);  // XCD swizzle (400=8*50)
  const int b = bs / 100;
  const int qb0 = (bs % 100) * 64;

  const u16* Qb = Qtm + ((size_t)b * NTOK + qb0 + wq * 32 + l31) * CAv;
  const u16* Kb = Ktm + (size_t)b * NTOK * CAv;
  const u16* Vb = Vcm + (size_t)b * CAv * NTOK;
  const int kv00 = half * 3200;

  // Q fragments (B-operand): lane(h,q=l31), k = 16*kk + 8h + j
  sh8 qf[8];
#pragma unroll
  for (int kk = 0; kk < 8; kk++) qf[kk] = *(const sh8*)(Qb + kk * 16 + h * 8);

  // V DMA source base: slot = w2*512 + j*64 + lane; c = w2*64 + j*8 + (lane>>3),
  // stored col16' = lane&7, content col16 = (lane&7) ^ (c&7)  [c&7 == (lane>>3)&7]
  const int colx = (lane & 7) ^ ((lane >> 3) & 7);
  const u16* vbase = Vb + (size_t)(wq * 64 + (lane >> 3)) * NTOK + kv00 + colx * 8;

  // K prefetch pointer: lane part = l31 row, h*8 col
  const u16* kp = Kb + ((size_t)kv00 + l31) * CAv + h * 8;
  sh8 kf[16];
#pragma unroll
  for (int s = 0; s < 2; s++)
#pragma unroll
    for (int kk = 0; kk < 8; kk++)
      kf[s * 8 + kk] = *(const sh8*)(kp + s * 32 * CAv + kk * 16);
  kp += 64 * CAv;

  // issue V DMA for tile 0 -> buf 0
  {
    unsigned char* db = smem + half * 16384 + wq * 8192;
#pragma unroll
    for (int j = 0; j < 8; j++)
      gl_lds16(vbase + (size_t)j * 8 * NTOK, (u16*)(db + j * 1024));
    vbase += 64;
  }

  f32x16 o[4];
#pragma unroll
  for (int i = 0; i < 4; i++) o[i] = zero16();
  float m = -1e30f, lsum = 0.f;

  // per-lane swizzled V-read byte offsets for kv-step 0..3
  int voff[4];
#pragma unroll
  for (int st = 0; st < 4; st++)
    voff[st] = l31 * 128 + (((2 * st + h) ^ (l31 & 7)) * 16);

  __syncthreads();  // drains DMA (vmcnt) + barrier: V tile 0 visible

  int cur = 0;
  for (int t = 0; t < 50; t++) {
    // 1. issue V DMA for t+1 into other buffer
    if (t < 49) {
      unsigned char* db = smem + ((cur ^ 1) * 2 + half) * 16384 + wq * 8192;
#pragma unroll
      for (int j = 0; j < 8; j++)
        gl_lds16(vbase + (size_t)j * 8 * NTOK, (u16*)(db + j * 1024));
      vbase += 64;
    }
    // 2. QK^T (S^T): A = K rows, B = Q
    f32x16 s0 = zero16(), s1 = zero16();
#pragma unroll
    for (int kk = 0; kk < 8; kk++) {
      s0 = __builtin_amdgcn_mfma_f32_32x32x16_bf16(kf[kk], qf[kk], s0, 0, 0, 0);
      s1 = __builtin_amdgcn_mfma_f32_32x32x16_bf16(kf[8 + kk], qf[kk], s1, 0, 0, 0);
    }
    // 3. prefetch K for t+1 (in flight across softmax+PV+barrier)
    if (t < 49) {
#pragma unroll
      for (int s = 0; s < 2; s++)
#pragma unroll
        for (int kk = 0; kk < 8; kk++)
          kf[s * 8 + kk] = *(const sh8*)(kp + s * 32 * CAv + kk * 16);
      kp += 64 * CAv;
    }
    // 4. online softmax (lane-local in q; one xor-32 hop for the row halves)
    float pmax = -1e30f;
#pragma unroll
    for (int r = 0; r < 16; r++) pmax = fmaxf(pmax, fmaxf(s0[r], s1[r]));
    pmax = fmaxf(pmax, __shfl_xor(pmax, 32));
    if (__any(pmax > m + 8.f)) {  // defer-max: rescale only on real growth
      float mnew = fmaxf(m, pmax);
      float al = __expf(m - mnew);
#pragma unroll
      for (int i = 0; i < 16; i++) {
        o[0][i] *= al; o[1][i] *= al; o[2][i] *= al; o[3][i] *= al;
      }
      lsum *= al;
      m = mnew;
    }
    f32x16 p0, p1;
#pragma unroll
    for (int r = 0; r < 16; r++) {
      p0[r] = __expf(s0[r] - m);
      p1[r] = __expf(s1[r] - m);
    }
    float ps = 0.f;
#pragma unroll
    for (int r = 0; r < 16; r++) ps += p0[r] + p1[r];
    ps += __shfl_xor(ps, 32);
    lsum += ps;
    // pack P -> bf16 dwords: pkm[s][rq] covers S-rows (r&3)+8*rq+4h' of subtile s
    unsigned pkm[2][4][2];
#pragma unroll
    for (int rq = 0; rq < 4; rq++) {
      pkm[0][rq][0] = pk2(p0[4 * rq + 0], p0[4 * rq + 1]);
      pkm[0][rq][1] = pk2(p0[4 * rq + 2], p0[4 * rq + 3]);
      pkm[1][rq][0] = pk2(p1[4 * rq + 0], p1[4 * rq + 1]);
      pkm[1][rq][1] = pk2(p1[4 * rq + 2], p1[4 * rq + 3]);
    }
    // 5. PV: per 16-kv step build B-frag (half local, half via xor-32), A = V from LDS
    const unsigned char* vb = smem + (cur * 2 + half) * 16384;
#pragma unroll
    for (int s = 0; s < 2; s++)
#pragma unroll
      for (int b2 = 0; b2 < 2; b2++) {
        unsigned ow0 = hb ? pkm[s][2 * b2 + 1][0] : pkm[s][2 * b2][0];
        unsigned ow1 = hb ? pkm[s][2 * b2 + 1][1] : pkm[s][2 * b2][1];
        unsigned sd0 = hb ? pkm[s][2 * b2][0] : pkm[s][2 * b2 + 1][0];
        unsigned sd1 = hb ? pkm[s][2 * b2][1] : pkm[s][2 * b2 + 1][1];
        unsigned rv0 = (unsigned)__shfl_xor((int)sd0, 32);
        unsigned rv1 = (unsigned)__shfl_xor((int)sd1, 32);
        uint4v fw = {hb ? rv0 : ow0, hb ? rv1 : ow1,
                     hb ? ow0 : rv0, hb ? ow1 : rv1};
        sh8 pf = __builtin_bit_cast(sh8, fw);
        const int st2 = s * 2 + b2;
#pragma unroll
        for (int ct = 0; ct < 4; ct++) {
          sh8 vf = *(const sh8*)(vb + ct * 4096 + voff[st2]);
          o[ct] = __builtin_amdgcn_mfma_f32_32x32x16_bf16(vf, pf, o[ct], 0, 0, 0);
        }
      }
    __syncthreads();  // drains DMA for t+1; publishes next buffer
    cur ^= 1;
  }

  // ---- KV-split merge: upper half -> LDS, lower half combines + writes ----
  float* OM = (float*)smem;             // [2][32][136] f32 (aliases V bufs)
  float* MLs = (float*)(smem + 65536);  // [wq][{m,l}][32]
  if (wv >= 2) {
    float* om = OM + (size_t)wq * 32 * 136 + (size_t)l31 * 136;
#pragma unroll
    for (int ct = 0; ct < 4; ct++)
#pragma unroll
      for (int rq = 0; rq < 4; rq++) {
        f32x4 v = {o[ct][4 * rq + 0], o[ct][4 * rq + 1],
                   o[ct][4 * rq + 2], o[ct][4 * rq + 3]};
        *(f32x4*)(om + ct * 32 + rq * 8 + h * 4) = v;
      }
    if (h == 0) {
      MLs[wq * 64 + l31] = m;
      MLs[wq * 64 + 32 + l31] = lsum;
    }
  }
  __syncthreads();
  if (wv < 2) {
    float m1 = MLs[wq * 64 + l31];
    float l1 = MLs[wq * 64 + 32 + l31];
    float mM = fmaxf(m, m1);
    float a0 = __expf(m - mM), a1 = __expf(m1 - mM);
    float L = lsum * a0 + l1 * a1;
    float f0 = a0 / L, f1 = a1 / L;
    const float* om = OM + (size_t)wq * 32 * 136 + (size_t)l31 * 136;
    float* op = Otm + ((size_t)b * NTOK + qb0 + wq * 32 + l31) * CAv;
#pragma unroll
    for (int ct = 0; ct < 4; ct++)
#pragma unroll
      for (int rq = 0; rq < 4; rq++) {
        f32x4 u = *(const f32x4*)(om + ct * 32 + rq * 8 + h * 4);
        f32x4 w;
#pragma unroll
        for (int i = 0; i < 4; i++)
          w[i] = o[ct][4 * rq + i] * f0 + u[i] * f1;
        *(f32x4*)(op + ct * 32 + rq * 8 + h * 4) = w;
      }
  }
}

// ---------------- output projection + residual ----------------
__global__ __launch_bounds__(512) void outproj(const float* __restrict__ met,
                                               const float* __restrict__ woT,
                                               const float* __restrict__ bo,
                                               const float* __restrict__ Otm,
                                               float* __restrict__ out) {
  const int bs = (blockIdx.x & 7) * 50 + (blockIdx.x >> 3);
  const int b = bs / 100;
  const int tokb = (bs % 100) * 64;
  const int tok = threadIdx.x & 63;
  const int chg = __builtin_amdgcn_readfirstlane(threadIdx.x >> 6);  // 0..7
  const float* op = Otm + ((size_t)b * NTOK + tokb + tok) * CAv;
  float acc[32];
#pragma unroll
  for (int j = 0; j < 32; j++) acc[j] = 0.f;
#pragma unroll 4
  for (int c = 0; c < CAv; c++) {
    float ov = op[c];
    const float* wt = woT + c * CMv + chg * 32;
#pragma unroll
    for (int j = 0; j < 32; j++) acc[j] = fmaf(wt[j], ov, acc[j]);
  }
#pragma unroll
  for (int j = 0; j < 32; j++) {
    int ch = chg * 32 + j;
    size_t idx = ((size_t)b * CMv + ch) * NTOK + tokb + tok;
    out[idx] = met[idx] + acc[j] + bo[ch];
  }
}

extern "C" void kernel_launch(void* const* d_in, const int* in_sizes, int n_in,
                              void* d_out, int out_size, void* d_ws, size_t ws_size,
                              hipStream_t stream) {
  const float* met = (const float*)d_in[0];
  const float* ter = (const float*)d_in[1];
  const float* wq = (const float*)d_in[2];
  const float* bq = (const float*)d_in[3];
  const float* wk = (const float*)d_in[4];
  const float* bk = (const float*)d_in[5];
  const float* wv = (const float*)d_in[6];
  const float* bv = (const float*)d_in[7];
  const float* wo = (const float*)d_in[8];
  const float* bo = (const float*)d_in[9];
  float* out = (float*)d_out;

  u16* Qtm = (u16*)d_ws;
  u16* Ktm = Qtm + (size_t)BB * NTOK * CAv;
  u16* Vcm = Ktm + (size_t)BB * NTOK * CAv;
  float* Otm = (float*)(Vcm + (size_t)BB * NTOK * CAv);
  float* wqT = Otm + (size_t)BB * NTOK * CAv;
  float* wkT = wqT + 256 * 128;
  float* wvT = wkT + 64 * 128;
  float* woT = wvT + 64 * 128;

  prepw<<<dim3(32), dim3(256), 0, stream>>>(wq, wk, wv, wo, wqT, wkT, wvT, woT);
  qproj<<<dim3(400), dim3(256), 0, stream>>>(met, wqT, bq, Qtm);
  kvproj<<<dim3(400), dim3(512), 0, stream>>>(ter, wkT, bk, wvT, bv, Ktm, Vcm);
  attn<<<dim3(400), dim3(256), 0, stream>>>(Qtm, Ktm, Vcm, Otm);
  outproj<<<dim3(400), dim3(512), 0, stream>>>(met, woT, bo, Otm, out);
}